// Round 11
// baseline (436.873 us; speedup 1.0000x reference)
//
#include <hip/hip_runtime.h>
#include <math.h>

#define NN 100000
#define NPAD 100096           // >= cdiv(NN,256)*256 (MFMA supertile coverage)
#define EE 800000
#define NHEADS 4
#define HID 48
#define FDIM (NHEADS * HID)   // 192
#define ROWB 384              // bf16 row bytes (192 * 2)
#define KPAD 64               // padded K for MFMA (real K = 48)
#define TLES 4                // 64-row tiles per gemm block
#define SCAN_CHUNK 2048
#define NBLK ((NN + SCAN_CHUNK - 1) / SCAN_CHUNK)  // 49
#define HIST_BLKS (EE / 256)  // 3125 exact

typedef unsigned int uint;
typedef unsigned short ushort;

#if __has_builtin(__builtin_amdgcn_exp2f)
#define EXP2(x) __builtin_amdgcn_exp2f(x)
#else
#define EXP2(x) exp2f(x)
#endif

struct U3 { uint x, y, z; };  // 12-byte, 4-aligned

typedef __attribute__((ext_vector_type(8))) short s16x8;   // 8 bf16 (4 VGPRs)
typedef __attribute__((ext_vector_type(4))) float f32x4;   // MFMA accumulator

// ---------------- bf16 helpers ----------------

__device__ __forceinline__ uint f2bf(float x) {   // RTN-even, 16-bit result
    uint u = __float_as_uint(x);
    return (u + 0x7FFFu + ((u >> 16) & 1u)) >> 16;
}
__device__ __forceinline__ float bfl(uint u) { return __uint_as_float(u << 16); }
__device__ __forceinline__ float bfh(uint u) { return __uint_as_float(u & 0xFFFF0000u); }

// ---------------- CSR build + W prep (fused) ----------------

__global__ void histwprep_k(const int* __restrict__ ei, int* __restrict__ cnt,
                            const float* __restrict__ Wl1, const float* __restrict__ Wr1,
                            const float* __restrict__ Wl2, const float* __restrict__ Wr2,
                            ushort* __restrict__ Wt1, ushort* __restrict__ Wt2) {
    int b = blockIdx.x;
    if (b < HIST_BLKS) {
        int e = b * 256 + threadIdx.x;
        atomicAdd(&cnt[ei[EE + e]], 1);
        return;
    }
    int t = (b - HIST_BLKS) * 256 + threadIdx.x;   // [0, 2*KPAD*384)
    int l = t / (KPAD * 384);
    int rem = t - l * (KPAD * 384);
    int k = rem / 384;
    int c = rem - k * 384;
    int cc = (c >= 192) ? c - 192 : c;
    const float* W = (l == 0) ? (c < 192 ? Wl1 : Wr1) : (c < 192 ? Wl2 : Wr2);
    float v = (k < 48) ? W[k * FDIM + cc] : 0.0f;
    uint hi = f2bf(v);
    float lo = v - bfl(hi);
    uint lob = f2bf(lo);
    ushort* Wt = (l == 0) ? Wt1 : Wt2;
    Wt[c * KPAD + k] = (ushort)hi;
    Wt[384 * KPAD + c * KPAD + k] = (ushort)lob;
}

__global__ void scan1_k(const int* __restrict__ cnt, int* __restrict__ rowptr,
                        int* __restrict__ bsum) {
    __shared__ int lds[256];
    int b = blockIdx.x, t = threadIdx.x;
    int base = b * SCAN_CHUNK + t * 8;
    int v[8], s = 0;
#pragma unroll
    for (int i = 0; i < 8; i++) { v[i] = (base + i < NN) ? cnt[base + i] : 0; s += v[i]; }
    lds[t] = s;
    __syncthreads();
    for (int off = 1; off < 256; off <<= 1) {
        int val = (t >= off) ? lds[t - off] : 0;
        __syncthreads();
        lds[t] += val;
        __syncthreads();
    }
    if (t == 255) bsum[b] = lds[255];
    int run = lds[t] - s;
#pragma unroll
    for (int i = 0; i < 8; i++) {
        if (base + i < NN) rowptr[base + i] = run;
        run += v[i];
    }
}

__global__ void scan3_k(int* __restrict__ rowptr, const int* __restrict__ bsum,
                        const int* __restrict__ cnt, int2* __restrict__ rc) {
    __shared__ int pref[64];
    int t = threadIdx.x;
    if (t < 64) pref[t] = (t < NBLK) ? bsum[t] : 0;
    __syncthreads();
    if (t == 0) {
        int acc = 0;
        for (int b = 0; b < NBLK; b++) { int v = pref[b]; pref[b] = acc; acc += v; }
    }
    __syncthreads();
    int i = blockIdx.x * 256 + t;
    if (i < NN) {
        int rp = rowptr[i] + pref[i / SCAN_CHUNK];
        rowptr[i] = rp;
        rc[i] = make_int2(rp, cnt[i]);
    }
}

__global__ void scatter_k(const int* __restrict__ ei, const int* __restrict__ rowptr,
                          int* __restrict__ fill, int* __restrict__ esrc) {
    int e = blockIdx.x * blockDim.x + threadIdx.x;
    if (e >= EE) return;
    int d = ei[EE + e];
    int pos = rowptr[d] + atomicAdd(&fill[d], 1);
    esrc[pos] = ei[e];
}

// ---------------- layer0 VALU gemm (K=3), bf16 outputs ----------------
__launch_bounds__(192)
__global__ void gemm2_k(const float* __restrict__ x,
                        const float* __restrict__ Wl, const float* __restrict__ bl,
                        const float* __restrict__ Wr, const float* __restrict__ br,
                        uint* __restrict__ xlb, uint* __restrict__ xrb) {
    const int DIN = 3;
    __shared__ float xs[32][53];
    int t = threadIdx.x;
    int f4 = t % 48, nb = t / 48;
    int node0 = blockIdx.x * 32;

    for (int idx = t; idx < 32 * DIN; idx += 192) {
        int n = idx / DIN, k = idx - n * DIN;
        xs[n][k] = x[(size_t)(node0 + n) * DIN + k];
    }
    __syncthreads();

    float4 accl[8], accr[8];
    {
        float4 bl4 = *(const float4*)(bl + f4 * 4);
        float4 br4 = *(const float4*)(br + f4 * 4);
#pragma unroll
        for (int r = 0; r < 8; r++) { accl[r] = bl4; accr[r] = br4; }
    }

#pragma unroll
    for (int k = 0; k < DIN; k++) {
        float4 wl4 = *(const float4*)(Wl + k * FDIM + f4 * 4);
        float4 wr4 = *(const float4*)(Wr + k * FDIM + f4 * 4);
#pragma unroll
        for (int r = 0; r < 8; r++) {
            float xv = xs[nb * 8 + r][k];
            accl[r].x = fmaf(xv, wl4.x, accl[r].x);
            accl[r].y = fmaf(xv, wl4.y, accl[r].y);
            accl[r].z = fmaf(xv, wl4.z, accl[r].z);
            accl[r].w = fmaf(xv, wl4.w, accl[r].w);
            accr[r].x = fmaf(xv, wr4.x, accr[r].x);
            accr[r].y = fmaf(xv, wr4.y, accr[r].y);
            accr[r].z = fmaf(xv, wr4.z, accr[r].z);
            accr[r].w = fmaf(xv, wr4.w, accr[r].w);
        }
    }

#pragma unroll
    for (int r = 0; r < 8; r++) {
        size_t n = (size_t)node0 + nb * 8 + r;
        uint2 pl, pr;
        pl.x = f2bf(accl[r].x) | (f2bf(accl[r].y) << 16);
        pl.y = f2bf(accl[r].z) | (f2bf(accl[r].w) << 16);
        pr.x = f2bf(accr[r].x) | (f2bf(accr[r].y) << 16);
        pr.y = f2bf(accr[r].z) | (f2bf(accr[r].w) << 16);
        *(uint2*)((char*)xlb + n * ROWB + f4 * 8) = pl;
        *(uint2*)((char*)xrb + n * ROWB + f4 * 8) = pr;
    }
}

// ---------------- MFMA gemm for layers 1,2 (B in registers, private-LDS repack) ----------------
__launch_bounds__(256)
__global__ void gemm_mfma_k(const ushort* __restrict__ xbf,   // [NPAD][KPAD]
                            const ushort* __restrict__ Wt,    // [2][384][KPAD]
                            const float* __restrict__ bl, const float* __restrict__ br,
                            ushort* __restrict__ xlb, ushort* __restrict__ xrb) {
    __shared__ ushort cs[4][16][104];
    int cg = blockIdx.x & 3;
    int n0 = (blockIdx.x >> 2) * (64 * TLES);
    int wave = threadIdx.x >> 6, lane = threadIdx.x & 63;
    int l15 = lane & 15, l16 = lane >> 4;
    int k8 = l16 * 8;

    s16x8 vbh0[6], vbh1[6], vbl0[6], vbl1[6];
    float bv[6];
#pragma unroll
    for (int ct = 0; ct < 6; ct++) {
        int cglob = cg * 96 + ct * 16 + l15;
        bv[ct] = (cglob < 192) ? bl[cglob] : br[cglob - 192];
        const ushort* bp = Wt + (size_t)cglob * KPAD + k8;
        vbh0[ct] = *(const s16x8*)(bp);
        vbh1[ct] = *(const s16x8*)(bp + 32);
        vbl0[ct] = *(const s16x8*)(bp + 384 * KPAD);
        vbl1[ct] = *(const s16x8*)(bp + 384 * KPAD + 32);
    }

    int colbase = cg * 96;
    ushort* outm = (colbase < 192) ? xlb : xrb;
    int cb = (colbase >= 192) ? colbase - 192 : colbase;

    const ushort* ap = xbf + (size_t)(n0 + wave * 16 + l15) * KPAD + k8;
    s16x8 a0 = *(const s16x8*)(ap);
    s16x8 a1 = *(const s16x8*)(ap + 32);

#pragma unroll
    for (int t = 0; t < TLES; t++) {
        s16x8 na0, na1;
        if (t + 1 < TLES) {
            const ushort* np = ap + (size_t)(t + 1) * 64 * KPAD;
            na0 = *(const s16x8*)(np);
            na1 = *(const s16x8*)(np + 32);
        }
        f32x4 acc[6];
#pragma unroll
        for (int ct = 0; ct < 6; ct++) {
            acc[ct] = (f32x4){bv[ct], bv[ct], bv[ct], bv[ct]};
            acc[ct] = __builtin_amdgcn_mfma_f32_16x16x32_bf16(a0, vbh0[ct], acc[ct], 0, 0, 0);
            acc[ct] = __builtin_amdgcn_mfma_f32_16x16x32_bf16(a1, vbh1[ct], acc[ct], 0, 0, 0);
            acc[ct] = __builtin_amdgcn_mfma_f32_16x16x32_bf16(a0, vbl0[ct], acc[ct], 0, 0, 0);
            acc[ct] = __builtin_amdgcn_mfma_f32_16x16x32_bf16(a1, vbl1[ct], acc[ct], 0, 0, 0);
        }
#pragma unroll
        for (int ct = 0; ct < 6; ct++)
#pragma unroll
            for (int r = 0; r < 4; r++)
                cs[wave][l16 * 4 + r][ct * 16 + l15] = (ushort)f2bf(acc[ct][r]);
        int nb0 = n0 + t * 64 + wave * 16;
#pragma unroll
        for (int i = 0; i < 3; i++) {
            int idx = lane + i * 64;
            int row = idx / 12, q = idx - row * 12;
            int node = nb0 + row;
            if (node < NN) {
                uint4 v = *(const uint4*)(&cs[wave][row][q * 8]);
                *(uint4*)(outm + (size_t)node * FDIM + cb + q * 8) = v;
            }
        }
        if (t + 1 < TLES) { a0 = na0; a1 = na1; }
    }
}

// ---------------- fused GATv2 layer ----------------
template <int CTRL>
__device__ __forceinline__ float dpp_add(float x) {
    int v = __builtin_amdgcn_update_dpp(0, __float_as_int(x), CTRL, 0xF, 0xF, true);
    return x + __int_as_float(v);
}
__device__ __forceinline__ float red8(float x) {
    x = dpp_add<0x141>(x);  // row_half_mirror
    x = dpp_add<0x04E>(x);  // quad_perm xor2
    x = dpp_add<0x0B1>(x);  // quad_perm xor1
    return x;
}
__device__ __forceinline__ float swz_add16(float x) {  // x + lane^16 partner (within 32)
    int v = __builtin_amdgcn_ds_swizzle(__float_as_int(x), 0x401F);
    return x + __int_as_float(v);
}

// Online-softmax pair update with defer-max fast path (exact: c==1 when m unchanged).
#define GAT_PAIR(CU, VALID)                                                      \
    {                                                                            \
        float ca0 = bfl(CU.x), ca1 = bfh(CU.x), ca2 = bfl(CU.y);                 \
        float ca3 = bfh(CU.y), ca4 = bfl(CU.z), ca5 = bfh(CU.z);                 \
        float t0 = ca0 + r0; t0 = fmaxf(t0, 0.2f * t0);                          \
        float t1 = ca1 + r1; t1 = fmaxf(t1, 0.2f * t1);                          \
        float t2 = ca2 + r2; t2 = fmaxf(t2, 0.2f * t2);                          \
        float t3 = ca3 + r3; t3 = fmaxf(t3, 0.2f * t3);                          \
        float t4 = ca4 + r4; t4 = fmaxf(t4, 0.2f * t4);                          \
        float t5 = ca5 + r5; t5 = fmaxf(t5, 0.2f * t5);                          \
        float l = red8(fmaf(t0, w0, fmaf(t1, w1, fmaf(t2, w2,                    \
                       fmaf(t3, w3, fmaf(t4, w4, t5 * w5))))));                  \
        if (__all((l <= m) | (int)!(VALID))) {                                   \
            float p = (VALID) ? EXP2(l - m) : 0.0f;                              \
            s += p;                                                              \
            o0 = fmaf(p, ca0, o0);                                               \
            o1 = fmaf(p, ca1, o1);                                               \
            o2 = fmaf(p, ca2, o2);                                               \
            o3 = fmaf(p, ca3, o3);                                               \
            o4 = fmaf(p, ca4, o4);                                               \
            o5 = fmaf(p, ca5, o5);                                               \
        } else {                                                                 \
            float mn = (VALID) ? fmaxf(m, l) : m;                                \
            float p = (VALID) ? EXP2(l - mn) : 0.0f;                             \
            float c = EXP2(m - mn);                                              \
            s = fmaf(s, c, p);                                                   \
            o0 = fmaf(o0, c, p * ca0);                                           \
            o1 = fmaf(o1, c, p * ca1);                                           \
            o2 = fmaf(o2, c, p * ca2);                                           \
            o3 = fmaf(o3, c, p * ca3);                                           \
            o4 = fmaf(o4, c, p * ca4);                                           \
            o5 = fmaf(o5, c, p * ca5);                                           \
            m = mn;                                                              \
        }                                                                        \
    }

#define BPERM(K) __builtin_amdgcn_ds_bpermute((((K) & 31) << 3) + half4, my_src)

// lane = 32*half + 8*h + j ; holds features [h*48 + j*6, +6).
__global__ void gat_node_k(const uint* __restrict__ xlb, const uint* __restrict__ xrb,
                           const int2* __restrict__ rc, const int* __restrict__ esrc,
                           const float* __restrict__ att, const float* __restrict__ bias,
                           ushort* __restrict__ xbf_out,
                           const float* __restrict__ headw, const float* __restrict__ headb,
                           float* __restrict__ out) {
    int wid = (blockIdx.x * blockDim.x + threadIdx.x) >> 6;
    int lane = threadIdx.x & 63;
    if (wid >= NN) return;
    int d = wid;
    int half = lane >> 5;
    int hb = lane & 31;
    int h = hb >> 3;
    int j = hb & 7;
    int boff = h * 96 + j * 12;
    int half4 = half << 2;

    const float LOG2E = 1.4426950408889634f;
    const float* ap = att + h * HID + j * 6;
    float w0 = ap[0] * LOG2E, w1 = ap[1] * LOG2E, w2 = ap[2] * LOG2E;
    float w3 = ap[3] * LOG2E, w4 = ap[4] * LOG2E, w5 = ap[5] * LOG2E;

    const char* xlc = (const char*)xlb;
    const char* xrc = (const char*)xrb;

    // xr row: single-use -> non-temporal (don't evict gather lines)
    const uint* urp = (const uint*)(xrc + (size_t)d * ROWB + boff);
    U3 ur;
    ur.x = __builtin_nontemporal_load(urp);
    ur.y = __builtin_nontemporal_load(urp + 1);
    ur.z = __builtin_nontemporal_load(urp + 2);
    float r0 = bfl(ur.x), r1 = bfh(ur.x), r2 = bfl(ur.y);
    float r3 = bfh(ur.y), r4 = bfl(ur.z), r5 = bfh(ur.z);

    // self xl row: part of the gather-reuse stream -> normal (cache it)
    U3 us = *(const U3*)(xlc + (size_t)d * ROWB + boff);
    float a0 = bfl(us.x), a1 = bfh(us.x), a2 = bfl(us.y);
    float a3 = bfh(us.y), a4 = bfl(us.z), a5 = bfh(us.z);
    float v0 = a0 + r0; v0 = fmaxf(v0, 0.2f * v0);
    float v1 = a1 + r1; v1 = fmaxf(v1, 0.2f * v1);
    float v2 = a2 + r2; v2 = fmaxf(v2, 0.2f * v2);
    float v3 = a3 + r3; v3 = fmaxf(v3, 0.2f * v3);
    float v4 = a4 + r4; v4 = fmaxf(v4, 0.2f * v4);
    float v5 = a5 + r5; v5 = fmaxf(v5, 0.2f * v5);
    float lself = red8(fmaf(v0, w0, fmaf(v1, w1, fmaf(v2, w2,
                       fmaf(v3, w3, fmaf(v4, w4, v5 * w5))))));

    float m = half ? -3.0e38f : lself;
    float s = half ? 0.0f : 1.0f;
    float o0 = half ? 0.f : a0, o1 = half ? 0.f : a1, o2 = half ? 0.f : a2;
    float o3 = half ? 0.f : a3, o4 = half ? 0.f : a4, o5 = half ? 0.f : a5;

    int2 rcv;
    rcv.x = __builtin_nontemporal_load(&rc[d].x);
    rcv.y = __builtin_nontemporal_load(&rc[d].y);
    int start = __builtin_amdgcn_readfirstlane(rcv.x);
    int deg = __builtin_amdgcn_readfirstlane(rcv.y);

    for (int cb = 0; cb < deg; cb += 64) {
        int rem = deg - cb; if (rem > 64) rem = 64;
        int my_src = 0;
        if (lane < rem) my_src = __builtin_nontemporal_load(&esrc[start + cb + lane]);
        int npairs = (rem + 1) >> 1;

        // depth-3: rows for pairs i, i+1 in registers, pair i+2's row in flight
        int sA = BPERM(0);
        int sB = BPERM(1);
        U3 b0 = *(const U3*)(xlc + (uint)sA * (uint)ROWB + (uint)boff);
        int sC = BPERM(2);
        U3 b1 = *(const U3*)(xlc + (uint)sB * (uint)ROWB + (uint)boff);

        for (int i = 0; i < npairs - 1; i++) {
            U3 b2 = *(const U3*)(xlc + (uint)sC * (uint)ROWB + (uint)boff);
            sC = BPERM(i + 3);
            GAT_PAIR(b0, true);
            b0 = b1; b1 = b2;
        }
        {
            bool valid = (((npairs - 1) << 1) + half) < rem;
            GAT_PAIR(b0, valid);
        }
    }

    // merge the two halves' states
    float m2 = __shfl_xor(m, 32);
    float s2 = __shfl_xor(s, 32);
    float mn = fmaxf(m, m2);
    float c1 = EXP2(m - mn), c2 = EXP2(m2 - mn);
    float sm = fmaf(s, c1, s2 * c2);
    float inv = 1.0f / (sm + 1e-16f);
    float q0 = fmaf(o0, c1, __shfl_xor(o0, 32) * c2) * inv;
    float q1 = fmaf(o1, c1, __shfl_xor(o1, 32) * c2) * inv;
    float q2 = fmaf(o2, c1, __shfl_xor(o2, 32) * c2) * inv;
    float q3 = fmaf(o3, c1, __shfl_xor(o3, 32) * c2) * inv;
    float q4 = fmaf(o4, c1, __shfl_xor(o4, 32) * c2) * inv;
    float q5 = fmaf(o5, c1, __shfl_xor(o5, 32) * c2) * inv;

    // mean over heads: xor8 via DPP row_ror:8, xor16 via ds_swizzle
    q0 = dpp_add<0x128>(q0); q0 = swz_add16(q0);
    q1 = dpp_add<0x128>(q1); q1 = swz_add16(q1);
    q2 = dpp_add<0x128>(q2); q2 = swz_add16(q2);
    q3 = dpp_add<0x128>(q3); q3 = swz_add16(q3);
    q4 = dpp_add<0x128>(q4); q4 = swz_add16(q4);
    q5 = dpp_add<0x128>(q5); q5 = swz_add16(q5);

    if (lane < 8) {
        const float* bp = bias + j * 6;
        float y0 = fmaf(q0, 0.25f, bp[0]);
        float y1 = fmaf(q1, 0.25f, bp[1]);
        float y2 = fmaf(q2, 0.25f, bp[2]);
        float y3 = fmaf(q3, 0.25f, bp[3]);
        float y4 = fmaf(q4, 0.25f, bp[4]);
        float y5 = fmaf(q5, 0.25f, bp[5]);
        y0 = y0 > 0.f ? y0 : (EXP2(y0 * LOG2E) - 1.0f);
        y1 = y1 > 0.f ? y1 : (EXP2(y1 * LOG2E) - 1.0f);
        y2 = y2 > 0.f ? y2 : (EXP2(y2 * LOG2E) - 1.0f);
        y3 = y3 > 0.f ? y3 : (EXP2(y3 * LOG2E) - 1.0f);
        y4 = y4 > 0.f ? y4 : (EXP2(y4 * LOG2E) - 1.0f);
        y5 = y5 > 0.f ? y5 : (EXP2(y5 * LOG2E) - 1.0f);
        if (headw) {
            const float* hp = headw + j * 6;
            float pd = fmaf(y0, hp[0], fmaf(y1, hp[1], fmaf(y2, hp[2],
                       fmaf(y3, hp[3], fmaf(y4, hp[4], y5 * hp[5])))));
            pd = red8(pd);
            if (j == 0) {
                float acc = pd + headb[0];
                __builtin_nontemporal_store(
                    fmaxf(acc, 0.f) + log1pf(expf(-fabsf(acc))), &out[d]);
            }
        } else {
            uint p0 = f2bf(y0) | (f2bf(y1) << 16);
            uint p1 = f2bf(y2) | (f2bf(y3) << 16);
            uint p2 = f2bf(y4) | (f2bf(y5) << 16);
            uint* qo = (uint*)(xbf_out + (size_t)d * KPAD + j * 6);
            __builtin_nontemporal_store(p0, qo);
            __builtin_nontemporal_store(p1, qo + 1);
            __builtin_nontemporal_store(p2, qo + 2);
        }
    }
}

static inline int cdiv(long a, long b) { return (int)((a + b - 1) / b); }

extern "C" void kernel_launch(void* const* d_in, const int* in_sizes, int n_in,
                              void* d_out, int out_size, void* d_ws, size_t ws_size,
                              hipStream_t stream) {
    const float* x0 = (const float*)d_in[0];
    const int* ei = (const int*)d_in[1];
    const float* Wl[3] = {(const float*)d_in[2], (const float*)d_in[8], (const float*)d_in[14]};
    const float* bl[3] = {(const float*)d_in[3], (const float*)d_in[9], (const float*)d_in[15]};
    const float* Wr[3] = {(const float*)d_in[4], (const float*)d_in[10], (const float*)d_in[16]};
    const float* br[3] = {(const float*)d_in[5], (const float*)d_in[11], (const float*)d_in[17]};
    const float* att[3] = {(const float*)d_in[6], (const float*)d_in[12], (const float*)d_in[18]};
    const float* bb[3] = {(const float*)d_in[7], (const float*)d_in[13], (const float*)d_in[19]};
    const float* hw = (const float*)d_in[20];
    const float* hb = (const float*)d_in[21];

    char* ws = (char*)d_ws;
    uint* xlb = (uint*)ws;      ws += (size_t)NN * ROWB;
    uint* xrb = (uint*)ws;      ws += (size_t)NN * ROWB;
    ushort* Wt1 = (ushort*)ws;  ws += (size_t)2 * 384 * KPAD * 2;
    ushort* Wt2 = (ushort*)ws;  ws += (size_t)2 * 384 * KPAD * 2;
    int* rowptr = (int*)ws;     ws += (size_t)NN * 4;
    int2* rc = (int2*)ws;       ws += (size_t)NN * 8;
    int* esrc = (int*)ws;       ws += (size_t)EE * 4;
    int* bsum = (int*)ws;       ws += (size_t)NBLK * 4;
    // contiguous zero-region: cnt | fill | xbf  (single memset)
    int* cnt = (int*)ws;        ws += (size_t)NN * 4;
    int* fill = (int*)ws;       ws += (size_t)NN * 4;
    ushort* xbf = (ushort*)ws;  ws += (size_t)NPAD * KPAD * 2;
    const size_t ZBYTES = (size_t)NN * 4 * 2 + (size_t)NPAD * KPAD * 2;

    // ---- once-per-launch prep ----
    hipMemsetAsync(cnt, 0, ZBYTES, stream);
    histwprep_k<<<HIST_BLKS + (2 * KPAD * 384) / 256, 256, 0, stream>>>(
        ei, cnt, Wl[1], Wr[1], Wl[2], Wr[2], Wt1, Wt2);
    scan1_k<<<NBLK, 256, 0, stream>>>(cnt, rowptr, bsum);
    scan3_k<<<cdiv(NN, 256), 256, 0, stream>>>(rowptr, bsum, cnt, rc);
    scatter_k<<<cdiv(EE, 256), 256, 0, stream>>>(ei, rowptr, fill, esrc);

    const int GAT_GRID = cdiv((long)NN * 64, 256);
    const int MFMA_GRID = cdiv(NN, 64 * TLES) * 4;

    // layer 0 (K=3, VALU gemm)
    gemm2_k<<<NN / 32, 192, 0, stream>>>(x0, Wl[0], bl[0], Wr[0], br[0], xlb, xrb);
    gat_node_k<<<GAT_GRID, 256, 0, stream>>>(xlb, xrb, rc, esrc, att[0], bb[0],
                                             xbf, nullptr, nullptr, nullptr);
    // layer 1 (MFMA)
    gemm_mfma_k<<<MFMA_GRID, 256, 0, stream>>>(xbf, Wt1, bl[1], br[1],
                                               (ushort*)xlb, (ushort*)xrb);
    gat_node_k<<<GAT_GRID, 256, 0, stream>>>(xlb, xrb, rc, esrc, att[1], bb[1],
                                             xbf, nullptr, nullptr, nullptr);
    // layer 2 (MFMA) -> fused head
    gemm_mfma_k<<<MFMA_GRID, 256, 0, stream>>>(xbf, Wt2, bl[2], br[2],
                                               (ushort*)xlb, (ushort*)xrb);
    gat_node_k<<<GAT_GRID, 256, 0, stream>>>(xlb, xrb, rc, esrc, att[2], bb[2],
                                             nullptr, hw, hb, (float*)d_out);
}

// Round 12
// 413.451 us; speedup vs baseline: 1.0567x; 1.0567x over previous
//
#include <hip/hip_runtime.h>
#include <math.h>

#define NN 100000
#define NPAD 100096           // >= cdiv(NN,256)*256 (MFMA supertile coverage)
#define EE 800000
#define NHEADS 4
#define HID 48
#define FDIM (NHEADS * HID)   // 192
#define ROWB 384              // bf16 row bytes (192 * 2)
#define KPAD 64               // padded K for MFMA (real K = 48)
#define TLES 4                // 64-row tiles per gemm block
#define SCAN_CHUNK 2048
#define NBLK ((NN + SCAN_CHUNK - 1) / SCAN_CHUNK)  // 49
#define HIST_BLKS (EE / 256)  // 3125 exact

typedef unsigned int uint;
typedef unsigned short ushort;

#if __has_builtin(__builtin_amdgcn_exp2f)
#define EXP2(x) __builtin_amdgcn_exp2f(x)
#else
#define EXP2(x) exp2f(x)
#endif

struct U3 { uint x, y, z; };  // 12-byte, 4-aligned

typedef __attribute__((ext_vector_type(8))) short s16x8;   // 8 bf16 (4 VGPRs)
typedef __attribute__((ext_vector_type(4))) float f32x4;   // MFMA accumulator

// ---------------- bf16 helpers ----------------

__device__ __forceinline__ uint f2bf(float x) {   // RTN-even, 16-bit result
    uint u = __float_as_uint(x);
    return (u + 0x7FFFu + ((u >> 16) & 1u)) >> 16;
}
__device__ __forceinline__ float bfl(uint u) { return __uint_as_float(u << 16); }
__device__ __forceinline__ float bfh(uint u) { return __uint_as_float(u & 0xFFFF0000u); }

// ---------------- CSR build + W prep (fused) ----------------

__global__ void histwprep_k(const int* __restrict__ ei, int* __restrict__ cnt,
                            const float* __restrict__ Wl1, const float* __restrict__ Wr1,
                            const float* __restrict__ Wl2, const float* __restrict__ Wr2,
                            ushort* __restrict__ Wt1, ushort* __restrict__ Wt2) {
    int b = blockIdx.x;
    if (b < HIST_BLKS) {
        int e = b * 256 + threadIdx.x;
        atomicAdd(&cnt[ei[EE + e]], 1);
        return;
    }
    int t = (b - HIST_BLKS) * 256 + threadIdx.x;   // [0, 2*KPAD*384)
    int l = t / (KPAD * 384);
    int rem = t - l * (KPAD * 384);
    int k = rem / 384;
    int c = rem - k * 384;
    int cc = (c >= 192) ? c - 192 : c;
    const float* W = (l == 0) ? (c < 192 ? Wl1 : Wr1) : (c < 192 ? Wl2 : Wr2);
    float v = (k < 48) ? W[k * FDIM + cc] : 0.0f;
    uint hi = f2bf(v);
    float lo = v - bfl(hi);
    uint lob = f2bf(lo);
    ushort* Wt = (l == 0) ? Wt1 : Wt2;
    Wt[c * KPAD + k] = (ushort)hi;
    Wt[384 * KPAD + c * KPAD + k] = (ushort)lob;
}

__global__ void scan1_k(const int* __restrict__ cnt, int* __restrict__ rowptr,
                        int* __restrict__ bsum) {
    __shared__ int lds[256];
    int b = blockIdx.x, t = threadIdx.x;
    int base = b * SCAN_CHUNK + t * 8;
    int v[8], s = 0;
#pragma unroll
    for (int i = 0; i < 8; i++) { v[i] = (base + i < NN) ? cnt[base + i] : 0; s += v[i]; }
    lds[t] = s;
    __syncthreads();
    for (int off = 1; off < 256; off <<= 1) {
        int val = (t >= off) ? lds[t - off] : 0;
        __syncthreads();
        lds[t] += val;
        __syncthreads();
    }
    if (t == 255) bsum[b] = lds[255];
    int run = lds[t] - s;
#pragma unroll
    for (int i = 0; i < 8; i++) {
        if (base + i < NN) rowptr[base + i] = run;
        run += v[i];
    }
}

__global__ void scan3_k(int* __restrict__ rowptr, const int* __restrict__ bsum,
                        const int* __restrict__ cnt, int2* __restrict__ rc) {
    __shared__ int pref[64];
    int t = threadIdx.x;
    if (t < 64) pref[t] = (t < NBLK) ? bsum[t] : 0;
    __syncthreads();
    if (t == 0) {
        int acc = 0;
        for (int b = 0; b < NBLK; b++) { int v = pref[b]; pref[b] = acc; acc += v; }
    }
    __syncthreads();
    int i = blockIdx.x * 256 + t;
    if (i < NN) {
        int rp = rowptr[i] + pref[i / SCAN_CHUNK];
        rowptr[i] = rp;
        rc[i] = make_int2(rp, cnt[i]);
    }
}

__global__ void scatter_k(const int* __restrict__ ei, const int* __restrict__ rowptr,
                          int* __restrict__ fill, int* __restrict__ esrc) {
    int e = blockIdx.x * blockDim.x + threadIdx.x;
    if (e >= EE) return;
    int d = ei[EE + e];
    int pos = rowptr[d] + atomicAdd(&fill[d], 1);
    esrc[pos] = ei[e];
}

// ---------------- layer0 VALU gemm (K=3), bf16 outputs ----------------
__launch_bounds__(192)
__global__ void gemm2_k(const float* __restrict__ x,
                        const float* __restrict__ Wl, const float* __restrict__ bl,
                        const float* __restrict__ Wr, const float* __restrict__ br,
                        uint* __restrict__ xlb, uint* __restrict__ xrb) {
    const int DIN = 3;
    __shared__ float xs[32][53];
    int t = threadIdx.x;
    int f4 = t % 48, nb = t / 48;
    int node0 = blockIdx.x * 32;

    for (int idx = t; idx < 32 * DIN; idx += 192) {
        int n = idx / DIN, k = idx - n * DIN;
        xs[n][k] = x[(size_t)(node0 + n) * DIN + k];
    }
    __syncthreads();

    float4 accl[8], accr[8];
    {
        float4 bl4 = *(const float4*)(bl + f4 * 4);
        float4 br4 = *(const float4*)(br + f4 * 4);
#pragma unroll
        for (int r = 0; r < 8; r++) { accl[r] = bl4; accr[r] = br4; }
    }

#pragma unroll
    for (int k = 0; k < DIN; k++) {
        float4 wl4 = *(const float4*)(Wl + k * FDIM + f4 * 4);
        float4 wr4 = *(const float4*)(Wr + k * FDIM + f4 * 4);
#pragma unroll
        for (int r = 0; r < 8; r++) {
            float xv = xs[nb * 8 + r][k];
            accl[r].x = fmaf(xv, wl4.x, accl[r].x);
            accl[r].y = fmaf(xv, wl4.y, accl[r].y);
            accl[r].z = fmaf(xv, wl4.z, accl[r].z);
            accl[r].w = fmaf(xv, wl4.w, accl[r].w);
            accr[r].x = fmaf(xv, wr4.x, accr[r].x);
            accr[r].y = fmaf(xv, wr4.y, accr[r].y);
            accr[r].z = fmaf(xv, wr4.z, accr[r].z);
            accr[r].w = fmaf(xv, wr4.w, accr[r].w);
        }
    }

#pragma unroll
    for (int r = 0; r < 8; r++) {
        size_t n = (size_t)node0 + nb * 8 + r;
        uint2 pl, pr;
        pl.x = f2bf(accl[r].x) | (f2bf(accl[r].y) << 16);
        pl.y = f2bf(accl[r].z) | (f2bf(accl[r].w) << 16);
        pr.x = f2bf(accr[r].x) | (f2bf(accr[r].y) << 16);
        pr.y = f2bf(accr[r].z) | (f2bf(accr[r].w) << 16);
        *(uint2*)((char*)xlb + n * ROWB + f4 * 8) = pl;
        *(uint2*)((char*)xrb + n * ROWB + f4 * 8) = pr;
    }
}

// ---------------- MFMA gemm for layers 1,2 (B in registers, private-LDS repack) ----------------
__launch_bounds__(256)
__global__ void gemm_mfma_k(const ushort* __restrict__ xbf,   // [NPAD][KPAD]
                            const ushort* __restrict__ Wt,    // [2][384][KPAD]
                            const float* __restrict__ bl, const float* __restrict__ br,
                            ushort* __restrict__ xlb, ushort* __restrict__ xrb) {
    __shared__ ushort cs[4][16][104];
    int cg = blockIdx.x & 3;
    int n0 = (blockIdx.x >> 2) * (64 * TLES);
    int wave = threadIdx.x >> 6, lane = threadIdx.x & 63;
    int l15 = lane & 15, l16 = lane >> 4;
    int k8 = l16 * 8;

    s16x8 vbh0[6], vbh1[6], vbl0[6], vbl1[6];
    float bv[6];
#pragma unroll
    for (int ct = 0; ct < 6; ct++) {
        int cglob = cg * 96 + ct * 16 + l15;
        bv[ct] = (cglob < 192) ? bl[cglob] : br[cglob - 192];
        const ushort* bp = Wt + (size_t)cglob * KPAD + k8;
        vbh0[ct] = *(const s16x8*)(bp);
        vbh1[ct] = *(const s16x8*)(bp + 32);
        vbl0[ct] = *(const s16x8*)(bp + 384 * KPAD);
        vbl1[ct] = *(const s16x8*)(bp + 384 * KPAD + 32);
    }

    int colbase = cg * 96;
    ushort* outm = (colbase < 192) ? xlb : xrb;
    int cb = (colbase >= 192) ? colbase - 192 : colbase;

    const ushort* ap = xbf + (size_t)(n0 + wave * 16 + l15) * KPAD + k8;
    s16x8 a0 = *(const s16x8*)(ap);
    s16x8 a1 = *(const s16x8*)(ap + 32);

#pragma unroll
    for (int t = 0; t < TLES; t++) {
        s16x8 na0, na1;
        if (t + 1 < TLES) {
            const ushort* np = ap + (size_t)(t + 1) * 64 * KPAD;
            na0 = *(const s16x8*)(np);
            na1 = *(const s16x8*)(np + 32);
        }
        f32x4 acc[6];
#pragma unroll
        for (int ct = 0; ct < 6; ct++) {
            acc[ct] = (f32x4){bv[ct], bv[ct], bv[ct], bv[ct]};
            acc[ct] = __builtin_amdgcn_mfma_f32_16x16x32_bf16(a0, vbh0[ct], acc[ct], 0, 0, 0);
            acc[ct] = __builtin_amdgcn_mfma_f32_16x16x32_bf16(a1, vbh1[ct], acc[ct], 0, 0, 0);
            acc[ct] = __builtin_amdgcn_mfma_f32_16x16x32_bf16(a0, vbl0[ct], acc[ct], 0, 0, 0);
            acc[ct] = __builtin_amdgcn_mfma_f32_16x16x32_bf16(a1, vbl1[ct], acc[ct], 0, 0, 0);
        }
#pragma unroll
        for (int ct = 0; ct < 6; ct++)
#pragma unroll
            for (int r = 0; r < 4; r++)
                cs[wave][l16 * 4 + r][ct * 16 + l15] = (ushort)f2bf(acc[ct][r]);
        int nb0 = n0 + t * 64 + wave * 16;
#pragma unroll
        for (int i = 0; i < 3; i++) {
            int idx = lane + i * 64;
            int row = idx / 12, q = idx - row * 12;
            int node = nb0 + row;
            if (node < NN) {
                uint4 v = *(const uint4*)(&cs[wave][row][q * 8]);
                *(uint4*)(outm + (size_t)node * FDIM + cb + q * 8) = v;
            }
        }
        if (t + 1 < TLES) { a0 = na0; a1 = na1; }
    }
}

// ---------------- fused GATv2 layer ----------------
template <int CTRL>
__device__ __forceinline__ float dpp_add(float x) {
    int v = __builtin_amdgcn_update_dpp(0, __float_as_int(x), CTRL, 0xF, 0xF, true);
    return x + __int_as_float(v);
}
__device__ __forceinline__ float red8(float x) {
    x = dpp_add<0x141>(x);  // row_half_mirror
    x = dpp_add<0x04E>(x);  // quad_perm xor2
    x = dpp_add<0x0B1>(x);  // quad_perm xor1
    return x;
}
__device__ __forceinline__ float swz_add16(float x) {  // x + lane^16 partner (within 32)
    int v = __builtin_amdgcn_ds_swizzle(__float_as_int(x), 0x401F);
    return x + __int_as_float(v);
}

// Online-softmax pair update with defer-max fast path (exact: c==1 when m unchanged).
#define GAT_PAIR(CU, VALID)                                                      \
    {                                                                            \
        float ca0 = bfl(CU.x), ca1 = bfh(CU.x), ca2 = bfl(CU.y);                 \
        float ca3 = bfh(CU.y), ca4 = bfl(CU.z), ca5 = bfh(CU.z);                 \
        float t0 = ca0 + r0; t0 = fmaxf(t0, 0.2f * t0);                          \
        float t1 = ca1 + r1; t1 = fmaxf(t1, 0.2f * t1);                          \
        float t2 = ca2 + r2; t2 = fmaxf(t2, 0.2f * t2);                          \
        float t3 = ca3 + r3; t3 = fmaxf(t3, 0.2f * t3);                          \
        float t4 = ca4 + r4; t4 = fmaxf(t4, 0.2f * t4);                          \
        float t5 = ca5 + r5; t5 = fmaxf(t5, 0.2f * t5);                          \
        float l = red8(fmaf(t0, w0, fmaf(t1, w1, fmaf(t2, w2,                    \
                       fmaf(t3, w3, fmaf(t4, w4, t5 * w5))))));                  \
        if (__all((l <= m) | (int)!(VALID))) {                                   \
            float p = (VALID) ? EXP2(l - m) : 0.0f;                              \
            s += p;                                                              \
            o0 = fmaf(p, ca0, o0);                                               \
            o1 = fmaf(p, ca1, o1);                                               \
            o2 = fmaf(p, ca2, o2);                                               \
            o3 = fmaf(p, ca3, o3);                                               \
            o4 = fmaf(p, ca4, o4);                                               \
            o5 = fmaf(p, ca5, o5);                                               \
        } else {                                                                 \
            float mn = (VALID) ? fmaxf(m, l) : m;                                \
            float p = (VALID) ? EXP2(l - mn) : 0.0f;                             \
            float c = EXP2(m - mn);                                              \
            s = fmaf(s, c, p);                                                   \
            o0 = fmaf(o0, c, p * ca0);                                           \
            o1 = fmaf(o1, c, p * ca1);                                           \
            o2 = fmaf(o2, c, p * ca2);                                           \
            o3 = fmaf(o3, c, p * ca3);                                           \
            o4 = fmaf(o4, c, p * ca4);                                           \
            o5 = fmaf(o5, c, p * ca5);                                           \
            m = mn;                                                              \
        }                                                                        \
    }

#define BPERM(K) __builtin_amdgcn_ds_bpermute((((K) & 31) << 3) + half4, my_src)

// lane = 32*half + 8*h + j ; holds features [h*48 + j*6, +6).
__global__ void gat_node_k(const uint* __restrict__ xlb, const uint* __restrict__ xrb,
                           const int2* __restrict__ rc, const int* __restrict__ esrc,
                           const float* __restrict__ att, const float* __restrict__ bias,
                           ushort* __restrict__ xbf_out,
                           const float* __restrict__ headw, const float* __restrict__ headb,
                           float* __restrict__ out) {
    int wid = (blockIdx.x * blockDim.x + threadIdx.x) >> 6;
    int lane = threadIdx.x & 63;
    if (wid >= NN) return;
    int d = wid;
    int half = lane >> 5;
    int hb = lane & 31;
    int h = hb >> 3;
    int j = hb & 7;
    int boff = h * 96 + j * 12;
    int half4 = half << 2;

    const float LOG2E = 1.4426950408889634f;
    const float* ap = att + h * HID + j * 6;
    float w0 = ap[0] * LOG2E, w1 = ap[1] * LOG2E, w2 = ap[2] * LOG2E;
    float w3 = ap[3] * LOG2E, w4 = ap[4] * LOG2E, w5 = ap[5] * LOG2E;

    const char* xlc = (const char*)xlb;
    const char* xrc = (const char*)xrb;

    U3 ur = *(const U3*)(xrc + (size_t)d * ROWB + boff);
    float r0 = bfl(ur.x), r1 = bfh(ur.x), r2 = bfl(ur.y);
    float r3 = bfh(ur.y), r4 = bfl(ur.z), r5 = bfh(ur.z);

    U3 us = *(const U3*)(xlc + (size_t)d * ROWB + boff);
    float a0 = bfl(us.x), a1 = bfh(us.x), a2 = bfl(us.y);
    float a3 = bfh(us.y), a4 = bfl(us.z), a5 = bfh(us.z);
    float v0 = a0 + r0; v0 = fmaxf(v0, 0.2f * v0);
    float v1 = a1 + r1; v1 = fmaxf(v1, 0.2f * v1);
    float v2 = a2 + r2; v2 = fmaxf(v2, 0.2f * v2);
    float v3 = a3 + r3; v3 = fmaxf(v3, 0.2f * v3);
    float v4 = a4 + r4; v4 = fmaxf(v4, 0.2f * v4);
    float v5 = a5 + r5; v5 = fmaxf(v5, 0.2f * v5);
    float lself = red8(fmaf(v0, w0, fmaf(v1, w1, fmaf(v2, w2,
                       fmaf(v3, w3, fmaf(v4, w4, v5 * w5))))));

    float m = half ? -3.0e38f : lself;
    float s = half ? 0.0f : 1.0f;
    float o0 = half ? 0.f : a0, o1 = half ? 0.f : a1, o2 = half ? 0.f : a2;
    float o3 = half ? 0.f : a3, o4 = half ? 0.f : a4, o5 = half ? 0.f : a5;

    int2 rcv = rc[d];
    int start = __builtin_amdgcn_readfirstlane(rcv.x);
    int deg = __builtin_amdgcn_readfirstlane(rcv.y);

    for (int cb = 0; cb < deg; cb += 64) {
        int rem = deg - cb; if (rem > 64) rem = 64;
        int my_src = 0;
        if (lane < rem) my_src = esrc[start + cb + lane];
        int npairs = (rem + 1) >> 1;

        // depth-3: rows for pairs i, i+1 in registers, pair i+2's row in flight
        int sA = BPERM(0);
        int sB = BPERM(1);
        U3 b0 = *(const U3*)(xlc + (uint)sA * (uint)ROWB + (uint)boff);
        int sC = BPERM(2);
        U3 b1 = *(const U3*)(xlc + (uint)sB * (uint)ROWB + (uint)boff);

        for (int i = 0; i < npairs - 1; i++) {
            U3 b2 = *(const U3*)(xlc + (uint)sC * (uint)ROWB + (uint)boff);
            sC = BPERM(i + 3);
            GAT_PAIR(b0, true);
            b0 = b1; b1 = b2;
        }
        {
            bool valid = (((npairs - 1) << 1) + half) < rem;
            GAT_PAIR(b0, valid);
        }
    }

    // merge the two halves' states
    float m2 = __shfl_xor(m, 32);
    float s2 = __shfl_xor(s, 32);
    float mn = fmaxf(m, m2);
    float c1 = EXP2(m - mn), c2 = EXP2(m2 - mn);
    float sm = fmaf(s, c1, s2 * c2);
    float inv = 1.0f / (sm + 1e-16f);
    float q0 = fmaf(o0, c1, __shfl_xor(o0, 32) * c2) * inv;
    float q1 = fmaf(o1, c1, __shfl_xor(o1, 32) * c2) * inv;
    float q2 = fmaf(o2, c1, __shfl_xor(o2, 32) * c2) * inv;
    float q3 = fmaf(o3, c1, __shfl_xor(o3, 32) * c2) * inv;
    float q4 = fmaf(o4, c1, __shfl_xor(o4, 32) * c2) * inv;
    float q5 = fmaf(o5, c1, __shfl_xor(o5, 32) * c2) * inv;

    // mean over heads: xor8 via DPP row_ror:8, xor16 via ds_swizzle
    q0 = dpp_add<0x128>(q0); q0 = swz_add16(q0);
    q1 = dpp_add<0x128>(q1); q1 = swz_add16(q1);
    q2 = dpp_add<0x128>(q2); q2 = swz_add16(q2);
    q3 = dpp_add<0x128>(q3); q3 = swz_add16(q3);
    q4 = dpp_add<0x128>(q4); q4 = swz_add16(q4);
    q5 = dpp_add<0x128>(q5); q5 = swz_add16(q5);

    if (lane < 8) {
        const float* bp = bias + j * 6;
        float y0 = fmaf(q0, 0.25f, bp[0]);
        float y1 = fmaf(q1, 0.25f, bp[1]);
        float y2 = fmaf(q2, 0.25f, bp[2]);
        float y3 = fmaf(q3, 0.25f, bp[3]);
        float y4 = fmaf(q4, 0.25f, bp[4]);
        float y5 = fmaf(q5, 0.25f, bp[5]);
        y0 = y0 > 0.f ? y0 : (EXP2(y0 * LOG2E) - 1.0f);
        y1 = y1 > 0.f ? y1 : (EXP2(y1 * LOG2E) - 1.0f);
        y2 = y2 > 0.f ? y2 : (EXP2(y2 * LOG2E) - 1.0f);
        y3 = y3 > 0.f ? y3 : (EXP2(y3 * LOG2E) - 1.0f);
        y4 = y4 > 0.f ? y4 : (EXP2(y4 * LOG2E) - 1.0f);
        y5 = y5 > 0.f ? y5 : (EXP2(y5 * LOG2E) - 1.0f);
        if (headw) {
            const float* hp = headw + j * 6;
            float pd = fmaf(y0, hp[0], fmaf(y1, hp[1], fmaf(y2, hp[2],
                       fmaf(y3, hp[3], fmaf(y4, hp[4], y5 * hp[5])))));
            pd = red8(pd);
            if (j == 0) {
                float acc = pd + headb[0];
                out[d] = fmaxf(acc, 0.f) + log1pf(expf(-fabsf(acc)));
            }
        } else {
            U3 pk;
            pk.x = f2bf(y0) | (f2bf(y1) << 16);
            pk.y = f2bf(y2) | (f2bf(y3) << 16);
            pk.z = f2bf(y4) | (f2bf(y5) << 16);
            *(U3*)(xbf_out + (size_t)d * KPAD + j * 6) = pk;
        }
    }
}

static inline int cdiv(long a, long b) { return (int)((a + b - 1) / b); }

extern "C" void kernel_launch(void* const* d_in, const int* in_sizes, int n_in,
                              void* d_out, int out_size, void* d_ws, size_t ws_size,
                              hipStream_t stream) {
    const float* x0 = (const float*)d_in[0];
    const int* ei = (const int*)d_in[1];
    const float* Wl[3] = {(const float*)d_in[2], (const float*)d_in[8], (const float*)d_in[14]};
    const float* bl[3] = {(const float*)d_in[3], (const float*)d_in[9], (const float*)d_in[15]};
    const float* Wr[3] = {(const float*)d_in[4], (const float*)d_in[10], (const float*)d_in[16]};
    const float* br[3] = {(const float*)d_in[5], (const float*)d_in[11], (const float*)d_in[17]};
    const float* att[3] = {(const float*)d_in[6], (const float*)d_in[12], (const float*)d_in[18]};
    const float* bb[3] = {(const float*)d_in[7], (const float*)d_in[13], (const float*)d_in[19]};
    const float* hw = (const float*)d_in[20];
    const float* hb = (const float*)d_in[21];

    char* ws = (char*)d_ws;
    uint* xlb = (uint*)ws;      ws += (size_t)NN * ROWB;
    uint* xrb = (uint*)ws;      ws += (size_t)NN * ROWB;
    ushort* Wt1 = (ushort*)ws;  ws += (size_t)2 * 384 * KPAD * 2;
    ushort* Wt2 = (ushort*)ws;  ws += (size_t)2 * 384 * KPAD * 2;
    int* rowptr = (int*)ws;     ws += (size_t)NN * 4;
    int2* rc = (int2*)ws;       ws += (size_t)NN * 8;
    int* esrc = (int*)ws;       ws += (size_t)EE * 4;
    int* bsum = (int*)ws;       ws += (size_t)NBLK * 4;
    // contiguous zero-region: cnt | fill | xbf  (single memset)
    int* cnt = (int*)ws;        ws += (size_t)NN * 4;
    int* fill = (int*)ws;       ws += (size_t)NN * 4;
    ushort* xbf = (ushort*)ws;  ws += (size_t)NPAD * KPAD * 2;
    const size_t ZBYTES = (size_t)NN * 4 * 2 + (size_t)NPAD * KPAD * 2;

    // ---- once-per-launch prep ----
    hipMemsetAsync(cnt, 0, ZBYTES, stream);
    histwprep_k<<<HIST_BLKS + (2 * KPAD * 384) / 256, 256, 0, stream>>>(
        ei, cnt, Wl[1], Wr[1], Wl[2], Wr[2], Wt1, Wt2);
    scan1_k<<<NBLK, 256, 0, stream>>>(cnt, rowptr, bsum);
    scan3_k<<<cdiv(NN, 256), 256, 0, stream>>>(rowptr, bsum, cnt, rc);
    scatter_k<<<cdiv(EE, 256), 256, 0, stream>>>(ei, rowptr, fill, esrc);

    const int GAT_GRID = cdiv((long)NN * 64, 256);
    const int MFMA_GRID = cdiv(NN, 64 * TLES) * 4;

    // layer 0 (K=3, VALU gemm)
    gemm2_k<<<NN / 32, 192, 0, stream>>>(x0, Wl[0], bl[0], Wr[0], br[0], xlb, xrb);
    gat_node_k<<<GAT_GRID, 256, 0, stream>>>(xlb, xrb, rc, esrc, att[0], bb[0],
                                             xbf, nullptr, nullptr, nullptr);
    // layer 1 (MFMA)
    gemm_mfma_k<<<MFMA_GRID, 256, 0, stream>>>(xbf, Wt1, bl[1], br[1],
                                               (ushort*)xlb, (ushort*)xrb);
    gat_node_k<<<GAT_GRID, 256, 0, stream>>>(xlb, xrb, rc, esrc, att[1], bb[1],
                                             xbf, nullptr, nullptr, nullptr);
    // layer 2 (MFMA) -> fused head
    gemm_mfma_k<<<MFMA_GRID, 256, 0, stream>>>(xbf, Wt2, bl[2], br[2],
                                               (ushort*)xlb, (ushort*)xrb);
    gat_node_k<<<GAT_GRID, 256, 0, stream>>>(xlb, xrb, rc, esrc, att[2], bb[2],
                                             nullptr, hw, hb, (float*)d_out);
}